// Round 2
// baseline (458.984 us; speedup 1.0000x reference)
//
#include <hip/hip_runtime.h>

// MultiHeadSelfAttention: B=4, S=2048, E=1024, H=16, Dh=64.
// ALL in/out tensors are FP32 (per reference + threshold forensics).
// Internally: fp32 -> bf16 conversion at LDS staging, bf16 MFMA compute,
// fp32 accumulate, bf16 intermediates in ws, fp32 final output.
//
// Stage 1: qkv_gemm  -> q,k,v bf16 in ws, head-major [bh][s][d]
// Stage 2: attn      -> flash-style online softmax, bf16 out [b*s][h*64+d] in ws
// Stage 3: out_gemm  -> @ Wo^T + bo -> d_out (fp32)

typedef __bf16 bf16;
typedef __attribute__((ext_vector_type(8))) short short8;
typedef __attribute__((ext_vector_type(4))) float floatx4;

#define MFMA16(a, b, c) __builtin_amdgcn_mfma_f32_16x16x32_bf16((a), (b), (c), 0, 0, 0)

#define LDS_STRIDE 56   // 128x32 tile rows padded 32->56 elems (112 B): 16B-aligned
#define ATT_STRIDE 136  // 128-col rows padded ->136 elems (272 B): 16B-aligned

// 8 contiguous elements -> 8 bf16 (as short8 bit pattern)
__device__ __forceinline__ short8 frag8(const bf16* __restrict__ p) {
    return *(const short8*)p;
}
__device__ __forceinline__ short8 frag8(const float* __restrict__ p) {
    const floatx4 a = *(const floatx4*)p;
    const floatx4 b = *(const floatx4*)(p + 4);
    short8 r;
#pragma unroll
    for (int j = 0; j < 4; j++) {
        r[j]     = __builtin_bit_cast(short, (bf16)a[j]);
        r[4 + j] = __builtin_bit_cast(short, (bf16)b[j]);
    }
    return r;
}

// ---------------------------------------------------------------------------
// 128x128-tile GEMM core: C[m][n] = sum_k A[m][k] * B[n][k]  (both K-contiguous)
// 256 threads = 4 waves (2x2 of 64x64), BK=32, single-buffered LDS.
// ---------------------------------------------------------------------------
template <typename TA, typename TB>
__device__ __forceinline__ void gemm128_core(
    const TA* __restrict__ A, const TB* __restrict__ B, int K,
    int m0, int n0, short* As, short* Bs, floatx4 acc[4][4])
{
    const int tid  = threadIdx.x;
    const int lane = tid & 63;
    const int w    = tid >> 6;
    const int wm   = w >> 1, wn = w & 1;
    const int g    = lane >> 4, c = lane & 15;
    const int lrow = tid >> 2;        // 0..63
    const int lc8  = (tid & 3) * 8;   // 0,8,16,24

#pragma unroll
    for (int mi = 0; mi < 4; mi++)
#pragma unroll
        for (int ni = 0; ni < 4; ni++)
            acc[mi][ni] = (floatx4){0.f, 0.f, 0.f, 0.f};

    for (int k0 = 0; k0 < K; k0 += 32) {
        *(short8*)(As + lrow * LDS_STRIDE + lc8) =
            frag8(A + (size_t)(m0 + lrow) * K + k0 + lc8);
        *(short8*)(As + (lrow + 64) * LDS_STRIDE + lc8) =
            frag8(A + (size_t)(m0 + lrow + 64) * K + k0 + lc8);
        *(short8*)(Bs + lrow * LDS_STRIDE + lc8) =
            frag8(B + (size_t)(n0 + lrow) * K + k0 + lc8);
        *(short8*)(Bs + (lrow + 64) * LDS_STRIDE + lc8) =
            frag8(B + (size_t)(n0 + lrow + 64) * K + k0 + lc8);
        __syncthreads();

        short8 af[4], bfr[4];
#pragma unroll
        for (int mi = 0; mi < 4; mi++)
            af[mi] = *(const short8*)(As + (wm * 64 + mi * 16 + c) * LDS_STRIDE + g * 8);
#pragma unroll
        for (int ni = 0; ni < 4; ni++)
            bfr[ni] = *(const short8*)(Bs + (wn * 64 + ni * 16 + c) * LDS_STRIDE + g * 8);
#pragma unroll
        for (int mi = 0; mi < 4; mi++)
#pragma unroll
            for (int ni = 0; ni < 4; ni++)
                acc[mi][ni] = MFMA16(af[mi], bfr[ni], acc[mi][ni]);
        __syncthreads();
    }
}

// ---------------------------------------------------------------------------
// Stage 1: q/k/v = x @ W{q,k,v}^T + b, scattered to head-major [bh][s][64] (bf16)
// grid (8, 64, 3), block 256
// ---------------------------------------------------------------------------
__global__ __launch_bounds__(256) void qkv_gemm(
    const float* __restrict__ X,
    const float* __restrict__ Wq, const float* __restrict__ Wk, const float* __restrict__ Wv,
    const float* __restrict__ bq, const float* __restrict__ bk, const float* __restrict__ bv,
    bf16* __restrict__ qkv)
{
    __shared__ __align__(16) short As[128 * LDS_STRIDE];
    __shared__ __align__(16) short Bs[128 * LDS_STRIDE];

    const int z = blockIdx.z;
    const float* W    = (z == 0) ? Wq : (z == 1) ? Wk : Wv;
    const float* bias = (z == 0) ? bq : (z == 1) ? bk : bv;
    bf16* outz = qkv + (size_t)z * (8192u * 1024u);

    const int m0 = blockIdx.y * 128;
    const int n0 = blockIdx.x * 128;

    floatx4 acc[4][4];
    gemm128_core(X, W, 1024, m0, n0, As, Bs, acc);

    const int lane = threadIdx.x & 63;
    const int w = threadIdx.x >> 6;
    const int wm = w >> 1, wn = w & 1;
    const int g = lane >> 4, c = lane & 15;

#pragma unroll
    for (int ni = 0; ni < 4; ni++) {
        const int n = n0 + wn * 64 + ni * 16 + c;
        const float bb = bias[n];
        const int h = n >> 6, d = n & 63;
#pragma unroll
        for (int mi = 0; mi < 4; mi++) {
#pragma unroll
            for (int r = 0; r < 4; r++) {
                const int m = m0 + wm * 64 + mi * 16 + g * 4 + r;
                const int b = m >> 11, s = m & 2047;
                outz[(((size_t)((b << 4) | h)) * 2048 + s) * 64 + d] =
                    (bf16)(acc[mi][ni][r] + bb);
            }
        }
    }
}

// ---------------------------------------------------------------------------
// Stage 2: flash attention per (bh, 128-query block). grid (16, 64), block 256.
// Each wave: 32 queries. K-blocks of 128 keys, online softmax.
// ---------------------------------------------------------------------------
__global__ __launch_bounds__(256) void attn_kernel(
    const bf16* __restrict__ qkv, bf16* __restrict__ attn_out)
{
    __shared__ __align__(16) short Vt[64 * ATT_STRIDE];        // V^T: [d][key]
    __shared__ __align__(16) short Pl[4 * 32 * ATT_STRIDE];    // per-wave P: [32 q][128 key]

    const int bh = blockIdx.y;            // 0..63: b = bh>>4, h = bh&15
    const int q0 = blockIdx.x * 128;
    const size_t HSTRIDE = 2048u * 64u;
    const bf16* Q  = qkv + (size_t)bh * HSTRIDE;
    const bf16* Kp = qkv + 8192u * 1024u + (size_t)bh * HSTRIDE;
    const bf16* Vp = qkv + 2u * 8192u * 1024u + (size_t)bh * HSTRIDE;

    const int tid  = threadIdx.x;
    const int lane = tid & 63;
    const int w    = tid >> 6;
    const int g    = lane >> 4, c = lane & 15;
    const float SCALE = 0.03125f;  // 1/sqrt(1024)

    // Q fragments (A-layout: m = lane&15, k = 8*(lane>>4)+j), resident in regs
    short8 qf[2][2];
#pragma unroll
    for (int mi = 0; mi < 2; mi++)
#pragma unroll
        for (int ks = 0; ks < 2; ks++)
            qf[mi][ks] = *(const short8*)(Q + (size_t)(q0 + w * 32 + mi * 16 + c) * 64
                                            + ks * 32 + g * 8);

    floatx4 o[2][4];
#pragma unroll
    for (int mi = 0; mi < 2; mi++)
#pragma unroll
        for (int di = 0; di < 4; di++)
            o[mi][di] = (floatx4){0.f, 0.f, 0.f, 0.f};
    float m_run[2][4], l_run[2][4];
#pragma unroll
    for (int mi = 0; mi < 2; mi++)
#pragma unroll
        for (int r = 0; r < 4; r++) { m_run[mi][r] = -1e30f; l_run[mi][r] = 0.f; }

    for (int kb = 0; kb < 16; kb++) {
        const int k0 = kb * 128;

        // stage V^T into LDS: thread -> row kr=tid>>1, half d0=(tid&1)*32
        {
            const int kr = tid >> 1;
            const int d0 = (tid & 1) * 32;
#pragma unroll
            for (int i = 0; i < 4; i++) {
                short8 v = *(const short8*)(Vp + (size_t)(k0 + kr) * 64 + d0 + i * 8);
#pragma unroll
                for (int j = 0; j < 8; j++)
                    Vt[(d0 + i * 8 + j) * ATT_STRIDE + kr] = v[j];
            }
        }

        // S = Q K^T for this wave's 32 q x 128 keys (K frags direct from global)
        floatx4 sAcc[2][8];
#pragma unroll
        for (int mi = 0; mi < 2; mi++)
#pragma unroll
            for (int ni = 0; ni < 8; ni++)
                sAcc[mi][ni] = (floatx4){0.f, 0.f, 0.f, 0.f};
#pragma unroll
        for (int ks = 0; ks < 2; ks++) {
            short8 kf[8];
#pragma unroll
            for (int ni = 0; ni < 8; ni++)
                kf[ni] = *(const short8*)(Kp + (size_t)(k0 + ni * 16 + c) * 64
                                             + ks * 32 + g * 8);
#pragma unroll
            for (int mi = 0; mi < 2; mi++)
#pragma unroll
                for (int ni = 0; ni < 8; ni++)
                    sAcc[mi][ni] = MFMA16(qf[mi][ks], kf[ni], sAcc[mi][ni]);
        }

        // online softmax (row stats across 16-lane groups; row = g*4+r)
#pragma unroll
        for (int mi = 0; mi < 2; mi++) {
#pragma unroll
            for (int r = 0; r < 4; r++) {
                float mx = -1e30f;
#pragma unroll
                for (int ni = 0; ni < 8; ni++) mx = fmaxf(mx, sAcc[mi][ni][r]);
                mx = fmaxf(mx, __shfl_xor(mx, 1));
                mx = fmaxf(mx, __shfl_xor(mx, 2));
                mx = fmaxf(mx, __shfl_xor(mx, 4));
                mx = fmaxf(mx, __shfl_xor(mx, 8));
                const float mnew = fmaxf(m_run[mi][r], mx * SCALE);
                const float alpha = __expf(m_run[mi][r] - mnew);
                float sum = 0.f;
                const int prow = (w * 32 + mi * 16 + g * 4 + r) * ATT_STRIDE;
#pragma unroll
                for (int ni = 0; ni < 8; ni++) {
                    const float p = __expf(sAcc[mi][ni][r] * SCALE - mnew);
                    sum += p;
                    Pl[prow + ni * 16 + c] = __builtin_bit_cast(short, (bf16)p);
                }
                sum += __shfl_xor(sum, 1);
                sum += __shfl_xor(sum, 2);
                sum += __shfl_xor(sum, 4);
                sum += __shfl_xor(sum, 8);
                l_run[mi][r] = l_run[mi][r] * alpha + sum;
                m_run[mi][r] = mnew;
#pragma unroll
                for (int di = 0; di < 4; di++) o[mi][di][r] *= alpha;
            }
        }
        __syncthreads();  // Vt staged + P visible

        // O += P V   (A from Pl, B from Vt)
#pragma unroll
        for (int ks2 = 0; ks2 < 4; ks2++) {
            short8 pf[2], vf[4];
#pragma unroll
            for (int mi = 0; mi < 2; mi++)
                pf[mi] = *(const short8*)(Pl + w * 32 * ATT_STRIDE
                                             + (mi * 16 + c) * ATT_STRIDE + ks2 * 32 + g * 8);
#pragma unroll
            for (int di = 0; di < 4; di++)
                vf[di] = *(const short8*)(Vt + (di * 16 + c) * ATT_STRIDE + ks2 * 32 + g * 8);
#pragma unroll
            for (int mi = 0; mi < 2; mi++)
#pragma unroll
                for (int di = 0; di < 4; di++)
                    o[mi][di] = MFMA16(pf[mi], vf[di], o[mi][di]);
        }
        __syncthreads();  // all waves done with Vt before next stage
    }

    // epilogue: O /= l, write bf16 [b*2048+s][h*64+d]
    const int b = bh >> 4, h = bh & 15;
#pragma unroll
    for (int mi = 0; mi < 2; mi++) {
#pragma unroll
        for (int r = 0; r < 4; r++) {
            const float inv = 1.0f / l_run[mi][r];
            const int srow = q0 + w * 32 + mi * 16 + g * 4 + r;
#pragma unroll
            for (int di = 0; di < 4; di++) {
                attn_out[((size_t)(b * 2048 + srow)) * 1024 + h * 64 + di * 16 + c] =
                    (bf16)(o[mi][di][r] * inv);
            }
        }
    }
}

// ---------------------------------------------------------------------------
// Stage 3: out = attn @ Wo^T + bo -> fp32. grid (8, 64).
// ---------------------------------------------------------------------------
__global__ __launch_bounds__(256) void out_gemm(
    const bf16* __restrict__ A, const float* __restrict__ Wo,
    const float* __restrict__ bo, float* __restrict__ C)
{
    __shared__ __align__(16) short As[128 * LDS_STRIDE];
    __shared__ __align__(16) short Bs[128 * LDS_STRIDE];

    const int m0 = blockIdx.y * 128;
    const int n0 = blockIdx.x * 128;

    floatx4 acc[4][4];
    gemm128_core(A, Wo, 1024, m0, n0, As, Bs, acc);

    const int lane = threadIdx.x & 63;
    const int w = threadIdx.x >> 6;
    const int wm = w >> 1, wn = w & 1;
    const int g = lane >> 4, c = lane & 15;

#pragma unroll
    for (int ni = 0; ni < 4; ni++) {
        const int n = n0 + wn * 64 + ni * 16 + c;
        const float bb = bo[n];
#pragma unroll
        for (int mi = 0; mi < 4; mi++) {
#pragma unroll
            for (int r = 0; r < 4; r++) {
                const int m = m0 + wm * 64 + mi * 16 + g * 4 + r;
                C[(size_t)m * 1024 + n] = acc[mi][ni][r] + bb;
            }
        }
    }
}

// ---------------------------------------------------------------------------
extern "C" void kernel_launch(void* const* d_in, const int* in_sizes, int n_in,
                              void* d_out, int out_size, void* d_ws, size_t ws_size,
                              hipStream_t stream)
{
    const float* x  = (const float*)d_in[0];
    const float* Wq = (const float*)d_in[1];
    const float* bq = (const float*)d_in[2];
    const float* Wk = (const float*)d_in[3];
    const float* bk = (const float*)d_in[4];
    const float* Wv = (const float*)d_in[5];
    const float* bv = (const float*)d_in[6];
    const float* Wo = (const float*)d_in[7];
    const float* bo = (const float*)d_in[8];
    float* out = (float*)d_out;

    bf16* qkv  = (bf16*)d_ws;                       // 3 x 8192x1024 bf16 = 48 MB
    bf16* attn = qkv + 3u * 8192u * 1024u;          // 8192x1024 bf16 = 16 MB

    qkv_gemm<<<dim3(8, 64, 3), dim3(256), 0, stream>>>(x, Wq, Wk, Wv, bq, bk, bv, qkv);
    attn_kernel<<<dim3(16, 64), dim3(256), 0, stream>>>(qkv, attn);
    out_gemm<<<dim3(8, 64), dim3(256), 0, stream>>>(attn, Wo, bo, out);
}